// Round 8
// baseline (840.959 us; speedup 1.0000x reference)
//
#include <hip/hip_runtime.h>
#include <cstdint>

typedef unsigned short u16;
typedef __attribute__((ext_vector_type(8))) short bf16x8;
typedef __attribute__((ext_vector_type(4))) float f32x4;

#define DIM   1024
#define BATCH 4
#define SEQ   4096
#define E3    3072
#define MTOT  (BATCH*SEQ)   // 16384

// ---------- bf16 helpers (RNE) ----------
__device__ __forceinline__ u16 f2bf(float x) {
    union { float f; unsigned u; } v; v.f = x;
    unsigned r = v.u + 0x7FFFu + ((v.u >> 16) & 1u);
    return (u16)(r >> 16);
}

// ---------- async global->LDS 16B ----------
__device__ __forceinline__ void gl16(const void* g, void* l) {
    __builtin_amdgcn_global_load_lds(
        (const __attribute__((address_space(1))) void*)g,
        (__attribute__((address_space(3))) void*)l, 16, 0, 0);
}

// ---------------------------------------------------------------------------
// ROUND-8: occupancy over scheduling. Rounds 1-7: six distinct schedules on
// the 256^2/8-wave/128KB-LDS shape ALL landed at ~790 TF, MfmaUtil 33%,
// Occupancy 21.6%. Root cause: acc[8][4]=128 AGPR + ~108 VGPR = ~236 regs on
// the gfx950 unified file -> 2 waves/SIMD -> 1 block/CU -> every barrier
// convoys the whole CU; pipes sum (MFMA 2484 + LDS 2300 + VALU 1500 ~= 6500
// cy/K-64 measured) instead of overlapping. m97's 874-912 TF came from ~3
// blocks/CU of independent work hiding each block's drain (m114).
//
// GEMM mainloop: C[128x128] += A * B^T, bf16 k-major, K mult of 32.
// 256 thr = 4 waves (2m x 2n); per-wave 64x64 -> acc[4][4] = 64 AGPR,
// ~120 regs total -> __launch_bounds__(256,4) -> 4 waves/SIMD; LDS 32KB
// (2 x 16KB double buffer, BK=32) -> 4 blocks/CU. Simple m97 loop:
// stage(t+1) -> read frags -> 16 MFMA -> __syncthreads() (the vmcnt0 drain
// inside the barrier is hidden by the other 3 resident blocks).
//
// LDS fragment-identity chunks: frag f (16 rows x 32k) at f*1KB; lane L
// holds (row L&15, k (L>>4)*8..+8) -> linear ds_read_b128, 0 conflicts,
// matches global_load_lds linear dest. Buffer stride 8192 u16 (16KB):
// A frags [0,4096), B frags [4096,8192).
// ---------------------------------------------------------------------------
__device__ __forceinline__ void gemm128(
    const u16* __restrict__ A, int sA,
    const u16* __restrict__ B, int sB,
    int K, int m0, int n0,
    u16* lds, f32x4 acc[4][4])
{
    const int t  = threadIdx.x;
    const int w  = t >> 6, L = t & 63;
    const int rL = L & 15, kq = L >> 4;
    const int ia0 = 4*(w>>1);          // A-frag base (m)
    const int jb0 = 4*(w&1);           // B-frag base (n)

    // wave w stages A-frags {2w,2w+1} and B-frags {2w,2w+1}
    const size_t gA0 = (size_t)(m0 + 2*w*16 + rL)*sA + kq*8;
    const size_t gA1 = gA0 + (size_t)16*sA;
    const size_t gB0 = (size_t)(n0 + 2*w*16 + rL)*sB + kq*8;
    const size_t gB1 = gB0 + (size_t)16*sB;
    const int lA = 2*w*512 + L*8;          // u16 offsets
    const int lB = 4096 + 2*w*512 + L*8;

    const int NT = K >> 5;

    {   u16* b = lds;
        gl16(A + gA0, b + lA); gl16(A + gA1, b + lA + 512);
        gl16(B + gB0, b + lB); gl16(B + gB1, b + lB + 512); }
    __syncthreads();

    for (int tt = 0; tt < NT; ++tt) {
        if (tt+1 < NT) {
            u16* b = lds + ((tt+1)&1)*8192;
            const size_t k0 = (size_t)(tt+1)*32;
            gl16(A + gA0 + k0, b + lA); gl16(A + gA1 + k0, b + lA + 512);
            gl16(B + gB0 + k0, b + lB); gl16(B + gB1 + k0, b + lB + 512);
        }
        const u16* b = lds + (tt&1)*8192;
        bf16x8 av[4], bv[4];
        #pragma unroll
        for (int i = 0; i < 4; ++i) av[i] = *(const bf16x8*)&b[(ia0+i)*512 + L*8];
        #pragma unroll
        for (int j = 0; j < 4; ++j) bv[j] = *(const bf16x8*)&b[4096 + (jb0+j)*512 + L*8];
        #pragma unroll
        for (int i = 0; i < 4; ++i)
            #pragma unroll
            for (int j = 0; j < 4; ++j)
                acc[i][j] = __builtin_amdgcn_mfma_f32_16x16x32_bf16(av[i], bv[j], acc[i][j], 0,0,0);
        __syncthreads();   // drains vmcnt->publishes tile tt+1; protects buf reuse
    }
}

// ---------------------------------------------------------------------------
// elementwise: fp32 -> bf16
// ---------------------------------------------------------------------------
__global__ __launch_bounds__(256)
void cvt_bf16(const float* __restrict__ x, u16* __restrict__ y) {
    size_t i = ((size_t)blockIdx.x*256 + threadIdx.x)*4;
    float4 v = *(const float4*)&x[i];
    ushort4 h;
    h.x = f2bf(v.x); h.y = f2bf(v.y); h.z = f2bf(v.z); h.w = f2bf(v.w);
    *(ushort4*)&y[i] = h;
}

// ---------------------------------------------------------------------------
// QKV GEMM: A = Xbf, B = Wbf. Epilogue:
//   Q region: pre-scaled by 1/32, bf16, row-major  (pair-packed u32 stores)
//   K region: bf16, row-major                      (pair-packed u32 stores)
//   V region: bf16, transposed [b][d][s]           (ushort4 stores)
// XCD swizzle: nwg=3072 (gx=24,gy=128), cpx=384: chunk c = 16 m-rows x 24
// n-cols (A chunk 4MB ~ L2-resident).
// ---------------------------------------------------------------------------
__global__ __launch_bounds__(256,4)
void gemm_qkv(const u16* __restrict__ Xbf, const u16* __restrict__ Wbf,
              const float* __restrict__ bias,
              u16* __restrict__ Qh, u16* __restrict__ Kh,
              u16* __restrict__ Vth)
{
    __shared__ __align__(16) u16 lds[16384];   // 2 x 16KB
    f32x4 acc[4][4];
    #pragma unroll
    for (int i=0;i<4;++i)
        #pragma unroll
        for (int j=0;j<4;++j) acc[i][j] = (f32x4){0.f,0.f,0.f,0.f};

    const int F = blockIdx.y*24 + blockIdx.x;
    const int c = F & 7, s = F >> 3;           // s in [0,384)
    const int mrow = c*16 + (s & 15);          // [0,128)
    const int ncol = s >> 4;                   // [0,24)
    const int m0 = mrow*128, n0 = ncol*128;
    gemm128(Xbf, DIM, Wbf, DIM, DIM, m0, n0, lds, acc);

    const int t = threadIdx.x, w = t>>6, L = t&63;
    const int wm = 64*(w>>1), wn = 64*(w&1);
    const int cl = L&15, rq = (L>>4)*4;
    const int region = n0 >> 10;           // whole 128-block in one region
    const float qscale = 0.03125f;

    if (region < 2) {
        u16* Dst = region ? Kh : Qh;
        const float fs = region ? 1.0f : qscale;
        #pragma unroll
        for (int j = 0; j < 4; ++j) {
            float bc = bias[n0 + wn + j*16 + cl];
            #pragma unroll
            for (int i = 0; i < 4; ++i)
                #pragma unroll
                for (int r = 0; r < 4; ++r)
                    acc[i][j][r] = (acc[i][j][r] + bc)*fs;
        }
        const int d0 = (n0 & 1023) + wn;
        #pragma unroll
        for (int p = 0; p < 2; ++p) {
            const int nt0 = 2*p, nt1 = 2*p+1;
            #pragma unroll
            for (int i = 0; i < 4; ++i) {
                int row0 = m0 + wm + i*16 + rq;
                int bi = row0 >> 12, s0 = row0 & (SEQ-1);
                #pragma unroll
                for (int r = 0; r < 4; ++r) {
                    float v0 = acc[i][nt0][r], v1 = acc[i][nt1][r];
                    float x0 = __shfl_xor(v0, 1, 64);
                    float x1 = __shfl_xor(v1, 1, 64);
                    unsigned wv; int colb;
                    if ((cl & 1) == 0) {
                        wv   = (unsigned)f2bf(v0) | ((unsigned)f2bf(x0) << 16);
                        colb = nt0*16 + cl;
                    } else {
                        wv   = (unsigned)f2bf(x1) | ((unsigned)f2bf(v1) << 16);
                        colb = nt1*16 + (cl-1);
                    }
                    size_t idx = ((size_t)bi*SEQ + s0 + r)*DIM + d0 + colb;
                    *(unsigned*)&Dst[idx] = wv;
                }
            }
        }
    } else {
        #pragma unroll
        for (int j = 0; j < 4; ++j) {
            int col = n0 + wn + j*16 + cl;
            float bc = bias[col];
            int d = col & (DIM-1);
            #pragma unroll
            for (int i = 0; i < 4; ++i) {
                int row0 = m0 + wm + i*16 + rq;
                int bi = row0 >> 12, s0 = row0 & (SEQ-1);
                ushort4 hv;
                hv.x = f2bf(acc[i][j][0] + bc);
                hv.y = f2bf(acc[i][j][1] + bc);
                hv.z = f2bf(acc[i][j][2] + bc);
                hv.w = f2bf(acc[i][j][3] + bc);
                size_t base = ((size_t)bi*DIM + d)*SEQ + s0;
                *(ushort4*)&Vth[base] = hv;
            }
        }
    }
}

// ---------------------------------------------------------------------------
// Scores, all batches: S_b = Qscaled_b @ K_b^T -> bf16, pair-packed stores.
// XCD swizzle: nwg=4096, cpx=512. c -> (bz, m-half); within: 16 super-tiles
// of 4m x 8n (12 hot panels ~ 3MB, L2-resident).
// ---------------------------------------------------------------------------
__global__ __launch_bounds__(256,4)
void gemm_scores(const u16* __restrict__ Qh, const u16* __restrict__ Kh,
                 u16* __restrict__ S0, u16* __restrict__ S1,
                 u16* __restrict__ S2, u16* __restrict__ S3)
{
    __shared__ __align__(16) u16 lds[16384];
    f32x4 acc[4][4];
    #pragma unroll
    for (int i=0;i<4;++i)
        #pragma unroll
        for (int j=0;j<4;++j) acc[i][j] = (f32x4){0.f,0.f,0.f,0.f};

    const int F = (blockIdx.z*32 + blockIdx.y)*32 + blockIdx.x;
    const int c = F & 7, s = F >> 3;          // s in [0,512)
    const int st = s >> 5, v = s & 31;
    const int bz   = c >> 1;
    const int mrow = (c&1)*16 + (st>>2)*4 + (v>>3);  // [0,32)
    const int ncol = (st&3)*8 + (v&7);               // [0,32)
    const size_t qo = (size_t)bz*SEQ*DIM;
    const int m0 = mrow*128, n0 = ncol*128;
    gemm128(Qh + qo, DIM, Kh + qo, DIM, DIM, m0, n0, lds, acc);

    u16* Sb = (bz == 0) ? S0 : (bz == 1) ? S1 : (bz == 2) ? S2 : S3;
    const int t = threadIdx.x, w = t>>6, L = t&63;
    const int wm = 64*(w>>1), wn = 64*(w&1);
    const int cl = L&15, rq = (L>>4)*4;
    #pragma unroll
    for (int p = 0; p < 2; ++p) {
        const int nt0 = 2*p, nt1 = 2*p+1;
        #pragma unroll
        for (int i = 0; i < 4; ++i) {
            int row0 = m0 + wm + i*16 + rq;
            #pragma unroll
            for (int r = 0; r < 4; ++r) {
                float v0 = acc[i][nt0][r], v1 = acc[i][nt1][r];
                float x0 = __shfl_xor(v0, 1, 64);
                float x1 = __shfl_xor(v1, 1, 64);
                unsigned wv; int colb;
                if ((cl & 1) == 0) {
                    wv   = (unsigned)f2bf(v0) | ((unsigned)f2bf(x0) << 16);
                    colb = nt0*16 + cl;
                } else {
                    wv   = (unsigned)f2bf(x1) | ((unsigned)f2bf(v1) << 16);
                    colb = nt1*16 + (cl-1);
                }
                *(unsigned*)&Sb[(size_t)(row0 + r)*SEQ + n0 + wn + colb] = wv;
            }
        }
    }
}

// ---------------------------------------------------------------------------
// Row softmax over bf16 S (pre-scaled scores), P bf16 in place. 16384 rows.
// ---------------------------------------------------------------------------
__global__ __launch_bounds__(256)
void softmax_pack(u16* __restrict__ S0, u16* __restrict__ S1,
                  u16* __restrict__ S2, u16* __restrict__ S3)
{
    __shared__ float red[4];
    const int t = threadIdx.x, L = t & 63, w = t >> 6;
    const int gr = blockIdx.x, bz = gr >> 12, rr = gr & (SEQ-1);
    u16* Sb = (bz == 0) ? S0 : (bz == 1) ? S1 : (bz == 2) ? S2 : S3;
    u16* row = Sb + (size_t)rr*SEQ;

    float v[16];
    float m = -1e30f;
    #pragma unroll
    for (int j = 0; j < 2; ++j) {
        ushort4 x0 = *(const ushort4*)&row[t*8 + j*2048];
        ushort4 x1 = *(const ushort4*)&row[t*8 + j*2048 + 4];
        union { unsigned u; float f; } c;
        c.u = (unsigned)x0.x << 16; v[8*j+0] = c.f;
        c.u = (unsigned)x0.y << 16; v[8*j+1] = c.f;
        c.u = (unsigned)x0.z << 16; v[8*j+2] = c.f;
        c.u = (unsigned)x0.w << 16; v[8*j+3] = c.f;
        c.u = (unsigned)x1.x << 16; v[8*j+4] = c.f;
        c.u = (unsigned)x1.y << 16; v[8*j+5] = c.f;
        c.u = (unsigned)x1.z << 16; v[8*j+6] = c.f;
        c.u = (unsigned)x1.w << 16; v[8*j+7] = c.f;
    }
    #pragma unroll
    for (int i = 0; i < 16; ++i) m = fmaxf(m, v[i]);
    #pragma unroll
    for (int off = 32; off; off >>= 1) m = fmaxf(m, __shfl_xor(m, off, 64));
    if (L == 0) red[w] = m;
    __syncthreads();
    m = fmaxf(fmaxf(red[0],red[1]), fmaxf(red[2],red[3]));

    float s = 0.f;
    #pragma unroll
    for (int i = 0; i < 16; ++i) { v[i] = __expf(v[i] - m); s += v[i]; }
    #pragma unroll
    for (int off = 32; off; off >>= 1) s += __shfl_xor(s, off, 64);
    __syncthreads();
    if (L == 0) red[w] = s;
    __syncthreads();
    s = red[0]+red[1]+red[2]+red[3];
    const float inv = 1.0f / s;

    #pragma unroll
    for (int j = 0; j < 2; ++j) {
        ushort4 h0, h1;
        h0.x = f2bf(v[8*j+0]*inv); h0.y = f2bf(v[8*j+1]*inv);
        h0.z = f2bf(v[8*j+2]*inv); h0.w = f2bf(v[8*j+3]*inv);
        h1.x = f2bf(v[8*j+4]*inv); h1.y = f2bf(v[8*j+5]*inv);
        h1.z = f2bf(v[8*j+6]*inv); h1.w = f2bf(v[8*j+7]*inv);
        *(ushort4*)&row[t*8 + j*2048]     = h0;
        *(ushort4*)&row[t*8 + j*2048 + 4] = h1;
    }
}

// ---------------------------------------------------------------------------
// PV, all batches: O_b = P_b @ Vt_b^T -> fp32 (scalar stores = full lines)
// XCD swizzle: nwg=1024, cpx=128. c -> (bz, m-half); slot 16m x 8n.
// ---------------------------------------------------------------------------
__global__ __launch_bounds__(256,4)
void gemm_pv(const u16* __restrict__ P0, const u16* __restrict__ P1,
             const u16* __restrict__ P2, const u16* __restrict__ P3,
             const u16* __restrict__ Vth,
             float* __restrict__ O0, float* __restrict__ O1,
             float* __restrict__ O2, float* __restrict__ O3)
{
    __shared__ __align__(16) u16 lds[16384];
    f32x4 acc[4][4];
    #pragma unroll
    for (int i=0;i<4;++i)
        #pragma unroll
        for (int j=0;j<4;++j) acc[i][j] = (f32x4){0.f,0.f,0.f,0.f};

    const int F = (blockIdx.z*32 + blockIdx.y)*8 + blockIdx.x;
    const int c = F & 7, s = F >> 3;          // s in [0,128)
    const int bz   = c >> 1;
    const int mrow = (c&1)*16 + (s>>3);       // [0,32)
    const int ncol = s & 7;                   // [0,8)
    const u16* Pb = (bz == 0) ? P0 : (bz == 1) ? P1 : (bz == 2) ? P2 : P3;
    float*     Ob = (bz == 0) ? O0 : (bz == 1) ? O1 : (bz == 2) ? O2 : O3;
    const int m0 = mrow*128, n0 = ncol*128;
    gemm128(Pb, SEQ, Vth + (size_t)bz*DIM*SEQ, SEQ, SEQ, m0, n0, lds, acc);

    const int t = threadIdx.x, w = t>>6, L = t&63;
    const int wm = 64*(w>>1), wn = 64*(w&1);
    const int cl = L&15, rq = (L>>4)*4;
    #pragma unroll
    for (int j = 0; j < 4; ++j) {
        int col = n0 + wn + j*16 + cl;
        #pragma unroll
        for (int i = 0; i < 4; ++i) {
            int row0 = m0 + wm + i*16 + rq;
            #pragma unroll
            for (int r = 0; r < 4; ++r)
                Ob[(size_t)(row0 + r)*DIM + col] = acc[i][j][r];
        }
    }
}

// ---------------------------------------------------------------------------
// linear copy (float4), for O2/O3 parked in ws -> d_out second half
// ---------------------------------------------------------------------------
__global__ __launch_bounds__(256)
void copy_out(const float* __restrict__ src, float* __restrict__ dst)
{
    size_t i = ((size_t)blockIdx.x*256 + threadIdx.x)*4;
    *(float4*)&dst[i] = *(const float4*)&src[i];
}

// ---------------------------------------------------------------------------
extern "C" void kernel_launch(void* const* d_in, const int* in_sizes, int n_in,
                              void* d_out, int out_size, void* d_ws, size_t ws_size,
                              hipStream_t stream) {
    const float* X    = (const float*)d_in[0];
    const float* W    = (const float*)d_in[1];
    const float* bias = (const float*)d_in[2];
    float* out = (float*)d_out;

    const size_t MB = (size_t)1 << 20;
    if (ws_size < 192*MB) return;
    char* ws = (char*)d_ws;
    char* wo = (char*)d_out;
    // ws: Qh[0,32) Kh[32,64) Vth[64,96) S0[96,128) S1[128,160) S2[160,192)
    u16* Qh  = (u16*)ws;
    u16* Kh  = (u16*)(ws + 32*MB);
    u16* Vth = (u16*)(ws + 64*MB);
    u16* S0  = (u16*)(ws + 96*MB);
    u16* S1  = (u16*)(ws + 128*MB);
    u16* S2  = (u16*)(ws + 160*MB);
    // d_out during prologue: Xbf[0,32) Wbf[32,38); during attention: S3[32,64)
    u16* Xbf = (u16*)wo;
    u16* Wbf = (u16*)(wo + 32*MB);
    u16* S3  = (u16*)(wo + 32*MB);
    // pv outputs: O0,O1 -> d_out[0,32); O2,O3 -> dead Qh/Kh-front ws[0,32)
    float* O0 = (float*)wo;
    float* O1 = (float*)(wo + 16*MB);
    float* O2 = (float*)ws;
    float* O3 = (float*)(ws + 16*MB);

    cvt_bf16<<<MTOT*DIM/1024, 256, 0, stream>>>(X, Xbf);
    cvt_bf16<<<E3*DIM/1024,   256, 0, stream>>>(W, Wbf);

    gemm_qkv<<<dim3(24, 128), 256, 0, stream>>>(
        Xbf, Wbf, bias, Qh, Kh, Vth);

    gemm_scores<<<dim3(32, 32, BATCH), 256, 0, stream>>>(
        Qh, Kh, S0, S1, S2, S3);

    softmax_pack<<<MTOT, 256, 0, stream>>>(S0, S1, S2, S3);

    gemm_pv<<<dim3(8, 32, BATCH), 256, 0, stream>>>(
        S0, S1, S2, S3, Vth, O0, O1, O2, O3);

    // O2,O3 (32 MB in ws) -> d_out[32,64)
    copy_out<<<(32*MB/sizeof(float))/1024, 256, 0, stream>>>(
        (const float*)ws, out + 8*MB);   // 8M floats = 32 MB offset
}

// Round 9
// 524.435 us; speedup vs baseline: 1.6036x; 1.6036x over previous
//
#include <hip/hip_runtime.h>
#include <cstdint>

typedef unsigned short u16;
typedef __attribute__((ext_vector_type(8))) short bf16x8;
typedef __attribute__((ext_vector_type(4))) float f32x4;

#define DIM   1024
#define BATCH 4
#define SEQ   4096
#define E3    3072
#define MTOT  (BATCH*SEQ)   // 16384

// ---------- bf16 helpers (RNE) ----------
__device__ __forceinline__ u16 f2bf(float x) {
    union { float f; unsigned u; } v; v.f = x;
    unsigned r = v.u + 0x7FFFu + ((v.u >> 16) & 1u);
    return (u16)(r >> 16);
}

// ---------- async global->LDS 16B ----------
__device__ __forceinline__ void gl16(const void* g, void* l) {
    __builtin_amdgcn_global_load_lds(
        (const __attribute__((address_space(1))) void*)g,
        (__attribute__((address_space(3))) void*)l, 16, 0, 0);
}

// ---------------------------------------------------------------------------
// GEMM mainloop: C[256x256] += A * B^T, both bf16 k-major, K mult of 64,
// K/64 >= 2. 512 thr = 8 waves (2m x 4n); per-wave 128x64 -> acc[8][4].
//
// ROUND-9 THEORY: every round (1-8) sits at staged-bytes/time ~ 6 TB/s
// (scores 1GB/173us, pv-128^2 2GB/275us, qkv 768MB/130us) regardless of
// schedule or occupancy -> FEED-RATE bound. Cause: fragment-identity staging
// reads 16 rows x 64B per gl16 = half cache-lines on the L1-bypassing
// global_load_lds path -> effective L2/LLC/HBM feed halved. m201 (12.6 TB/s)
// stages 8 rows x FULL 128B lines with pre-swizzled sources + swizzled reads.
//
// New layout (per 64KB K-step buffer, double-buffered = 128KB):
//   A: [256 rows][64 k] row-major bf16 (128B rows), 16B-col XOR swizzle:
//      byte(r,c16) = r*128 + ((c16)^(r&7))*16.   B: same at +32KB.
//   Stage instr j of wave w: dest = buf + (w*32+j*8)*128 (linear, HW scatters
//   lane L to +L*16). Lane L thus lands at (r = w*32+j*8+(L>>3), c16_phys =
//   L&7) = logical c16 = (L&7)^(L>>3)  [since r&7 = L>>3]. Source reads that
//   k-chunk -> each gl16 covers 8 rows x full 128B lines. 8 gl16/wave/K-64.
//   Frag read (fi, ks): lane L (rL=L&15, kq=L>>4) -> u16 addr =
//   fi*1024 + rL*64 + ((ks*4+kq)^(rL&7))*8. Bank-uniform: 16B-slot index
//   (ks*4+kq)^(rL&7) hits each of 8 slots exactly 8x per wave -> no excess
//   conflict. Same logical (row,k) per lane as before -> MFMA unchanged.
//
// Schedule: 2 barriers per K-64, counted vmcnt(8) (never drains in-loop):
//   BARR (all waves done reading buf t-1) ; STAGE8(t+1) -> buf (t+1)&1 ;
//   vmcnt(8) completes buf t ; BARR (publish) ; 4-phase compute, barrier-
//   free -> compiler pipelines 24 ds_reads against 64 MFMAs (m97 mechanism).
// Hazards: stage(t+1) overwrites buf(t-1), whose readers all passed BARR1;
// compute(t) reads buf t&1 while stages write (t+1)&1. Tail: vmcnt(0).
// ---------------------------------------------------------------------------
__device__ __forceinline__ void gemm256(
    const u16* __restrict__ A, int sA,
    const u16* __restrict__ B, int sB,
    int K, int m0, int n0,
    u16* lds, f32x4 acc[8][4])
{
    const int tid = threadIdx.x;
    const int w   = tid >> 6, L = tid & 63;
    const int rL  = L & 15, kq = L >> 4;
    const int wg8 = (w>>2)*8;      // A-frag tile base (m): frags wg8..wg8+7
    const int jb4 = 4*(w&3);       // B-frag tile base (n): frags jb4..jb4+3

    // staging source: lane L -> row +(L>>3), k-chunk (L&7)^(L>>3)
    const int lr    = L >> 3;
    const int kperm = ((L & 7) ^ lr) * 8;
    const size_t gA0 = (size_t)(m0 + w*32 + lr) * sA + kperm;
    const size_t gB0 = (size_t)(n0 + w*32 + lr) * sB + kperm;
    const int dA = w*2048;            // u16; + j*512 per instr
    const int dB = 16384 + w*2048;

    // frag-read per-lane constants
    const int rdr = rL * 64;
    const int kp0 = ((0 + kq) ^ (rL & 7)) * 8;   // ks=0
    const int kp1 = ((4 + kq) ^ (rL & 7)) * 8;   // ks=1

    const int NT = K >> 6;

#define FEN    __builtin_amdgcn_sched_barrier(0)
#define BARR   __builtin_amdgcn_s_barrier()
#define VMW(n) asm volatile("s_waitcnt vmcnt(" #n ")")

#define STAGE8(tn) { u16* bb = lds + (((tn)&1)<<15); \
    const size_t kk = (size_t)(tn)*64; \
    gl16(A + gA0 + kk,                 bb + dA); \
    gl16(A + gA0 + (size_t) 8*sA + kk, bb + dA + 512); \
    gl16(A + gA0 + (size_t)16*sA + kk, bb + dA + 1024); \
    gl16(A + gA0 + (size_t)24*sA + kk, bb + dA + 1536); \
    gl16(B + gB0 + kk,                 bb + dB); \
    gl16(B + gB0 + (size_t) 8*sB + kk, bb + dB + 512); \
    gl16(B + gB0 + (size_t)16*sB + kk, bb + dB + 1024); \
    gl16(B + gB0 + (size_t)24*sB + kk, bb + dB + 1536); }

#define MFMA(a,b,c) __builtin_amdgcn_mfma_f32_16x16x32_bf16(a,b,c,0,0,0)

    STAGE8(0);

    for (int tt = 0; tt < NT; ++tt) {
        BARR;                                 // all waves done with buf tt-1
        if (tt+1 < NT) { STAGE8(tt+1); FEN; VMW(8); }
        else           { FEN; VMW(0); }
        FEN; BARR; FEN;                       // publish buf tt

        const u16* bc = lds + ((tt&1)<<15);
        bf16x8 av[4], bv[4];

        // (mh0, ks0)
        #pragma unroll
        for (int i=0;i<4;++i) av[i] = *(const bf16x8*)&bc[(wg8+i)*1024 + rdr + kp0];
        #pragma unroll
        for (int j=0;j<4;++j) bv[j] = *(const bf16x8*)&bc[16384 + (jb4+j)*1024 + rdr + kp0];
        #pragma unroll
        for (int i=0;i<4;++i)
            #pragma unroll
            for (int j=0;j<4;++j) acc[i][j] = MFMA(av[i], bv[j], acc[i][j]);
        // (mh1, ks0)
        #pragma unroll
        for (int i=0;i<4;++i) av[i] = *(const bf16x8*)&bc[(wg8+4+i)*1024 + rdr + kp0];
        #pragma unroll
        for (int i=0;i<4;++i)
            #pragma unroll
            for (int j=0;j<4;++j) acc[4+i][j] = MFMA(av[i], bv[j], acc[4+i][j]);
        // (mh0, ks1)
        #pragma unroll
        for (int i=0;i<4;++i) av[i] = *(const bf16x8*)&bc[(wg8+i)*1024 + rdr + kp1];
        #pragma unroll
        for (int j=0;j<4;++j) bv[j] = *(const bf16x8*)&bc[16384 + (jb4+j)*1024 + rdr + kp1];
        #pragma unroll
        for (int i=0;i<4;++i)
            #pragma unroll
            for (int j=0;j<4;++j) acc[i][j] = MFMA(av[i], bv[j], acc[i][j]);
        // (mh1, ks1)
        #pragma unroll
        for (int i=0;i<4;++i) av[i] = *(const bf16x8*)&bc[(wg8+4+i)*1024 + rdr + kp1];
        #pragma unroll
        for (int i=0;i<4;++i)
            #pragma unroll
            for (int j=0;j<4;++j) acc[4+i][j] = MFMA(av[i], bv[j], acc[4+i][j]);
    }

#undef STAGE8
#undef MFMA
#undef FEN
#undef BARR
#undef VMW
}

// ---------------------------------------------------------------------------
// elementwise: fp32 -> bf16
// ---------------------------------------------------------------------------
__global__ __launch_bounds__(256)
void cvt_bf16(const float* __restrict__ x, u16* __restrict__ y) {
    size_t i = ((size_t)blockIdx.x*256 + threadIdx.x)*4;
    float4 v = *(const float4*)&x[i];
    ushort4 h;
    h.x = f2bf(v.x); h.y = f2bf(v.y); h.z = f2bf(v.z); h.w = f2bf(v.w);
    *(ushort4*)&y[i] = h;
}

// ---------------------------------------------------------------------------
// QKV GEMM: A = Xbf, B = Wbf. Epilogue:
//   Q region: pre-scaled by 1/32, bf16, row-major  (pair-packed u32 stores)
//   K region: bf16, row-major                      (pair-packed u32 stores)
//   V region: bf16, transposed [b][d][s]           (ushort4 stores)
// XCD swizzle: nwg=768, cpx=96. chunk c = 8 m-rows x all 12 n-cols.
// ---------------------------------------------------------------------------
__global__ __launch_bounds__(512,2)
void gemm_qkv(const u16* __restrict__ Xbf, const u16* __restrict__ Wbf,
              const float* __restrict__ bias,
              u16* __restrict__ Qh, u16* __restrict__ Kh,
              u16* __restrict__ Vth)
{
    __shared__ __align__(16) u16 lds[65536];   // 2 x 64KB K-step buffers
    f32x4 acc[8][4];
    #pragma unroll
    for (int i=0;i<8;++i)
        #pragma unroll
        for (int j=0;j<4;++j) acc[i][j] = (f32x4){0.f,0.f,0.f,0.f};

    const int F = blockIdx.y*12 + blockIdx.x;   // gx=12, x-fastest
    const int c = F & 7, s = F >> 3;            // XCD chunk / slot
    const int mrow = c*8 + (s & 7);             // [0,64)
    const int ncol = s >> 3;                    // [0,12)
    const int m0 = mrow*256, n0 = ncol*256;
    gemm256(Xbf, DIM, Wbf, DIM, DIM, m0, n0, lds, acc);

    const int t = threadIdx.x, w = t>>6, L = t&63;
    const int wm = 128*(w>>2), wn = 64*(w&3);
    const int cl = L&15, rq = (L>>4)*4;
    const int region = n0 >> 10;           // whole 256-block in one region
    const float qscale = 0.03125f;

    if (region < 2) {
        u16* Dst = region ? Kh : Qh;
        const float fs = region ? 1.0f : qscale;
        #pragma unroll
        for (int j = 0; j < 4; ++j) {
            float bc = bias[n0 + wn + j*16 + cl];
            #pragma unroll
            for (int i = 0; i < 8; ++i)
                #pragma unroll
                for (int r = 0; r < 4; ++r)
                    acc[i][j][r] = (acc[i][j][r] + bc)*fs;
        }
        const int d0 = (n0 & 1023) + wn;
        #pragma unroll
        for (int p = 0; p < 2; ++p) {
            const int nt0 = 2*p, nt1 = 2*p+1;
            #pragma unroll
            for (int i = 0; i < 8; ++i) {
                int row0 = m0 + wm + i*16 + rq;
                int bi = row0 >> 12, s0 = row0 & (SEQ-1);
                #pragma unroll
                for (int r = 0; r < 4; ++r) {
                    float v0 = acc[i][nt0][r], v1 = acc[i][nt1][r];
                    float x0 = __shfl_xor(v0, 1, 64);
                    float x1 = __shfl_xor(v1, 1, 64);
                    unsigned wv; int colb;
                    if ((cl & 1) == 0) {
                        wv   = (unsigned)f2bf(v0) | ((unsigned)f2bf(x0) << 16);
                        colb = nt0*16 + cl;
                    } else {
                        wv   = (unsigned)f2bf(x1) | ((unsigned)f2bf(v1) << 16);
                        colb = nt1*16 + (cl-1);
                    }
                    size_t idx = ((size_t)bi*SEQ + s0 + r)*DIM + d0 + colb;
                    *(unsigned*)&Dst[idx] = wv;
                }
            }
        }
    } else {
        #pragma unroll
        for (int j = 0; j < 4; ++j) {
            int col = n0 + wn + j*16 + cl;
            float bc = bias[col];
            int d = col & (DIM-1);
            #pragma unroll
            for (int i = 0; i < 8; ++i) {
                int row0 = m0 + wm + i*16 + rq;
                int bi = row0 >> 12, s0 = row0 & (SEQ-1);
                ushort4 hv;
                hv.x = f2bf(acc[i][j][0] + bc);
                hv.y = f2bf(acc[i][j][1] + bc);
                hv.z = f2bf(acc[i][j][2] + bc);
                hv.w = f2bf(acc[i][j][3] + bc);
                size_t base = ((size_t)bi*DIM + d)*SEQ + s0;
                *(ushort4*)&Vth[base] = hv;
            }
        }
    }
}

// ---------------------------------------------------------------------------
// Scores, all batches: S_b = Qscaled_b @ K_b^T -> bf16, pair-packed stores.
// XCD swizzle: nwg=1024, cpx=128. chunk c = half-batch; 4 super-tiles 4m x 8n.
// ---------------------------------------------------------------------------
__global__ __launch_bounds__(512,2)
void gemm_scores(const u16* __restrict__ Qh, const u16* __restrict__ Kh,
                 u16* __restrict__ S0, u16* __restrict__ S1,
                 u16* __restrict__ S2, u16* __restrict__ S3)
{
    __shared__ __align__(16) u16 lds[65536];
    f32x4 acc[8][4];
    #pragma unroll
    for (int i=0;i<8;++i)
        #pragma unroll
        for (int j=0;j<4;++j) acc[i][j] = (f32x4){0.f,0.f,0.f,0.f};

    const int F = (blockIdx.z*16 + blockIdx.y)*16 + blockIdx.x;
    const int c = F & 7, s = F >> 3;           // XCD chunk / slot (cpx=128)
    const int st = s >> 5, v = s & 31;         // super-tile, within
    const int bz   = c >> 1;
    const int mrow = (c&1)*8 + (st>>1)*4 + (v>>3);   // [0,16)
    const int ncol = (st&1)*8 + (v&7);               // [0,16)
    const size_t qo = (size_t)bz*SEQ*DIM;
    const int m0 = mrow*256, n0 = ncol*256;
    gemm256(Qh + qo, DIM, Kh + qo, DIM, DIM, m0, n0, lds, acc);

    u16* Sb = (bz == 0) ? S0 : (bz == 1) ? S1 : (bz == 2) ? S2 : S3;
    const int t = threadIdx.x, w = t>>6, L = t&63;
    const int wm = 128*(w>>2), wn = 64*(w&3);
    const int cl = L&15, rq = (L>>4)*4;
    #pragma unroll
    for (int p = 0; p < 2; ++p) {
        const int nt0 = 2*p, nt1 = 2*p+1;
        #pragma unroll
        for (int i = 0; i < 8; ++i) {
            int row0 = m0 + wm + i*16 + rq;
            #pragma unroll
            for (int r = 0; r < 4; ++r) {
                float v0 = acc[i][nt0][r], v1 = acc[i][nt1][r];
                float x0 = __shfl_xor(v0, 1, 64);
                float x1 = __shfl_xor(v1, 1, 64);
                unsigned wv; int colb;
                if ((cl & 1) == 0) {
                    wv   = (unsigned)f2bf(v0) | ((unsigned)f2bf(x0) << 16);
                    colb = nt0*16 + cl;
                } else {
                    wv   = (unsigned)f2bf(x1) | ((unsigned)f2bf(v1) << 16);
                    colb = nt1*16 + (cl-1);
                }
                *(unsigned*)&Sb[(size_t)(row0 + r)*SEQ + n0 + wn + colb] = wv;
            }
        }
    }
}

// ---------------------------------------------------------------------------
// Row softmax over bf16 S (pre-scaled scores), P bf16 in place. 16384 rows.
// ---------------------------------------------------------------------------
__global__ __launch_bounds__(256)
void softmax_pack(u16* __restrict__ S0, u16* __restrict__ S1,
                  u16* __restrict__ S2, u16* __restrict__ S3)
{
    __shared__ float red[4];
    const int t = threadIdx.x, L = t & 63, w = t >> 6;
    const int gr = blockIdx.x, bz = gr >> 12, rr = gr & (SEQ-1);
    u16* Sb = (bz == 0) ? S0 : (bz == 1) ? S1 : (bz == 2) ? S2 : S3;
    u16* row = Sb + (size_t)rr*SEQ;

    float v[16];
    float m = -1e30f;
    #pragma unroll
    for (int j = 0; j < 2; ++j) {
        ushort4 x0 = *(const ushort4*)&row[t*8 + j*2048];
        ushort4 x1 = *(const ushort4*)&row[t*8 + j*2048 + 4];
        union { unsigned u; float f; } c;
        c.u = (unsigned)x0.x << 16; v[8*j+0] = c.f;
        c.u = (unsigned)x0.y << 16; v[8*j+1] = c.f;
        c.u = (unsigned)x0.z << 16; v[8*j+2] = c.f;
        c.u = (unsigned)x0.w << 16; v[8*j+3] = c.f;
        c.u = (unsigned)x1.x << 16; v[8*j+4] = c.f;
        c.u = (unsigned)x1.y << 16; v[8*j+5] = c.f;
        c.u = (unsigned)x1.z << 16; v[8*j+6] = c.f;
        c.u = (unsigned)x1.w << 16; v[8*j+7] = c.f;
    }
    #pragma unroll
    for (int i = 0; i < 16; ++i) m = fmaxf(m, v[i]);
    #pragma unroll
    for (int off = 32; off; off >>= 1) m = fmaxf(m, __shfl_xor(m, off, 64));
    if (L == 0) red[w] = m;
    __syncthreads();
    m = fmaxf(fmaxf(red[0],red[1]), fmaxf(red[2],red[3]));

    float s = 0.f;
    #pragma unroll
    for (int i = 0; i < 16; ++i) { v[i] = __expf(v[i] - m); s += v[i]; }
    #pragma unroll
    for (int off = 32; off; off >>= 1) s += __shfl_xor(s, off, 64);
    __syncthreads();
    if (L == 0) red[w] = s;
    __syncthreads();
    s = red[0]+red[1]+red[2]+red[3];
    const float inv = 1.0f / s;

    #pragma unroll
    for (int j = 0; j < 2; ++j) {
        ushort4 h0, h1;
        h0.x = f2bf(v[8*j+0]*inv); h0.y = f2bf(v[8*j+1]*inv);
        h0.z = f2bf(v[8*j+2]*inv); h0.w = f2bf(v[8*j+3]*inv);
        h1.x = f2bf(v[8*j+4]*inv); h1.y = f2bf(v[8*j+5]*inv);
        h1.z = f2bf(v[8*j+6]*inv); h1.w = f2bf(v[8*j+7]*inv);
        *(ushort4*)&row[t*8 + j*2048]     = h0;
        *(ushort4*)&row[t*8 + j*2048 + 4] = h1;
    }
}

// ---------------------------------------------------------------------------
// PV, all batches: O_b = P_b @ Vt_b^T -> fp32 (scalar stores = full lines)
// XCD swizzle: nwg=256, cpx=32. chunk c = half-batch (8m x 4n).
// ---------------------------------------------------------------------------
__global__ __launch_bounds__(512,2)
void gemm_pv(const u16* __restrict__ P0, const u16* __restrict__ P1,
             const u16* __restrict__ P2, const u16* __restrict__ P3,
             const u16* __restrict__ Vth,
             float* __restrict__ O0, float* __restrict__ O1,
             float* __restrict__ O2, float* __restrict__ O3)
{
    __shared__ __align__(16) u16 lds[65536];
    f32x4 acc[8][4];
    #pragma unroll
    for (int i=0;i<8;++i)
        #pragma unroll
        for (int j=0;j<4;++j) acc[i][j] = (f32x4){0.f,0.f,0.f,0.f};

    const int F = (blockIdx.z*16 + blockIdx.y)*4 + blockIdx.x;
    const int c = F & 7, s = F >> 3;           // XCD chunk / slot (cpx=32)
    const int bz   = c >> 1;
    const int mrow = (c&1)*8 + (s>>2);         // [0,16)
    const int ncol = s & 3;                    // [0,4)
    const u16* Pb = (bz == 0) ? P0 : (bz == 1) ? P1 : (bz == 2) ? P2 : P3;
    float*     Ob = (bz == 0) ? O0 : (bz == 1) ? O1 : (bz == 2) ? O2 : O3;
    const int m0 = mrow*256, n0 = ncol*256;
    gemm256(Pb, SEQ, Vth + (size_t)bz*DIM*SEQ, SEQ, SEQ, m0, n0, lds, acc);

    const int t = threadIdx.x, w = t>>6, L = t&63;
    const int wm = 128*(w>>2), wn = 64*(w&3);
    const int cl = L&15, rq = (L>>4)*4;
    #pragma unroll
    for (int j = 0; j < 4; ++j) {
        int col = n0 + wn + j*16 + cl;
        #pragma unroll
        for (int i = 0; i < 8; ++i) {
            int row0 = m0 + wm + i*16 + rq;
            #pragma unroll
            for (int r = 0; r < 4; ++r)
                Ob[(size_t)(row0 + r)*DIM + col] = acc[i][j][r];
        }
    }
}

// ---------------------------------------------------------------------------
// linear copy (float4), for O2/O3 parked in ws -> d_out second half
// ---------------------------------------------------------------------------
__global__ __launch_bounds__(256)
void copy_out(const float* __restrict__ src, float* __restrict__ dst)
{
    size_t i = ((size_t)blockIdx.x*256 + threadIdx.x)*4;
    *(float4*)&dst[i] = *(const float4*)&src[i];
}

// ---------------------------------------------------------------------------
extern "C" void kernel_launch(void* const* d_in, const int* in_sizes, int n_in,
                              void* d_out, int out_size, void* d_ws, size_t ws_size,
                              hipStream_t stream) {
    const float* X    = (const float*)d_in[0];
    const float* W    = (const float*)d_in[1];
    const float* bias = (const float*)d_in[2];
    float* out = (float*)d_out;

    const size_t MB = (size_t)1 << 20;
    if (ws_size < 192*MB) return;
    char* ws = (char*)d_ws;
    char* wo = (char*)d_out;
    // ws: Qh[0,32) Kh[32,64) Vth[64,96) S0[96,128) S1[128,160) S2[160,192)
    u16* Qh  = (u16*)ws;
    u16* Kh  = (u16*)(ws + 32*MB);
    u16* Vth = (u16*)(ws + 64*MB);
    u16* S0  = (u16*)(ws + 96*MB);
    u16* S1  = (u16*)(ws + 128*MB);
    u16* S2  = (u16*)(ws + 160*MB);
    // d_out during prologue: Xbf[0,32) Wbf[32,38); during attention: S3[32,64)
    u16* Xbf = (u16*)wo;
    u16* Wbf = (u16*)(wo + 32*MB);
    u16* S3  = (u16*)(wo + 32*MB);
    // pv outputs: O0,O1 -> d_out[0,32); O2,O3 -> dead Qh/Kh-front ws[0,32)
    float* O0 = (float*)wo;
    float* O1 = (float*)(wo + 16*MB);
    float* O2 = (float*)ws;
    float* O3 = (float*)(ws + 16*MB);

    cvt_bf16<<<MTOT*DIM/1024, 256, 0, stream>>>(X, Xbf);
    cvt_bf16<<<E3*DIM/1024,   256, 0, stream>>>(W, Wbf);

    gemm_qkv<<<dim3(E3/256, MTOT/256), 512, 0, stream>>>(
        Xbf, Wbf, bias, Qh, Kh, Vth);

    gemm_scores<<<dim3(SEQ/256, SEQ/256, BATCH), 512, 0, stream>>>(
        Qh, Kh, S0, S1, S2, S3);

    softmax_pack<<<MTOT, 256, 0, stream>>>(S0, S1, S2, S3);

    gemm_pv<<<dim3(DIM/256, SEQ/256, BATCH), 512, 0, stream>>>(
        S0, S1, S2, S3, Vth, O0, O1, O2, O3);

    // O2,O3 (32 MB in ws) -> d_out[32,64)
    copy_out<<<(32*MB/sizeof(float))/1024, 256, 0, stream>>>(
        (const float*)ws, out + 8*MB);   // 8M floats = 32 MB offset
}